// Round 8
// baseline (108.007 us; speedup 1.0000x reference)
//
#include <hip/hip_runtime.h>

constexpr int Bn = 8, Tn = 4096, Dn = 512, Hn = 512;
constexpr int Mn = Bn * Tn;            // 32768 rows
constexpr int CH = 64, NC = Tn / CH;   // 64 chunks of 64 steps

typedef __attribute__((ext_vector_type(8))) short s8v;       // 8 bf16
typedef __attribute__((ext_vector_type(4))) float f4v;       // MFMA acc
typedef __attribute__((ext_vector_type(8))) _Float16 h8v;    // 16B granule: a[0..3], b[0..3]
typedef unsigned short ushort_t;

typedef __attribute__((address_space(1))) const void gv_t;   // global src for load_lds
typedef __attribute__((address_space(3))) void lv_t;         // LDS dst for load_lds

__device__ __forceinline__ short f2bf(float f) {
  unsigned u = __float_as_uint(f);
  u = (u + 0x7fffu + ((u >> 16) & 1u)) >> 16;   // RNE
  return (short)u;
}

// W fp32 [h][512] -> bf16 tiles of 128 rows x 32 k in MFMA-fragment order.
// Tile lb = rt*16 + kt; chunk c = (r>>4)*64 + k8*16 + (r&15).
// Blocks [0,64) = Wz, [64,128) = Wh.
__global__ __launch_bounds__(256) void convert_w(
    const float* __restrict__ Wz, const float* __restrict__ Wh,
    ushort_t* __restrict__ Wzb, ushort_t* __restrict__ Whb) {
  int bx = blockIdx.x, tid = threadIdx.x;
  const float* src;
  ushort_t* dst;
  int lb;
  if (bx < 64) { src = Wz; dst = Wzb; lb = bx; }
  else         { src = Wh; dst = Whb; lb = bx - 64; }
  const float* tsrc = src + ((size_t)(lb >> 4) * 128) * Dn + (lb & 15) * 32;
#pragma unroll
  for (int p = 0; p < 2; p++) {
    int idx = tid + p * 256;
    int r = idx >> 2, k8 = idx & 3;
    const float4* sv = reinterpret_cast<const float4*>(tsrc + (size_t)r * Dn + k8 * 8);
    float4 f0 = sv[0], f1 = sv[1];
    s8v v;
    v[0] = f2bf(f0.x); v[1] = f2bf(f0.y); v[2] = f2bf(f0.z); v[3] = f2bf(f0.w);
    v[4] = f2bf(f1.x); v[5] = f2bf(f1.y); v[6] = f2bf(f1.z); v[7] = f2bf(f1.w);
    int c = (r >> 4) * 64 + k8 * 16 + (r & 15);
    *reinterpret_cast<s8v*>(&dst[((size_t)lb * 512 + c) * 8]) = v;
  }
}

// Fused: fp32 X -> bf16 staging (in-kernel convert) + dual GEMM + activations
// + chunk summaries. 256M x 128H tile, BK=64, 8 waves, 128KB LDS dbuf,
// 1 barrier per K-step (all staging drains before it), counted vmcnt,
// setprio around MFMA cluster, XCD-affinity swizzle (X fetched once).
__global__ __launch_bounds__(512, 2) void gemm_act(
    const float* __restrict__ X, const ushort_t* __restrict__ Wzb,
    const ushort_t* __restrict__ Whb,
    const float* __restrict__ bzp, const float* __restrict__ bhp,
    h8v* __restrict__ cab, float* __restrict__ cA, float* __restrict__ cB) {
  __shared__ __align__(16) ushort_t lds[2 * 32768];   // 2 x 64KB

  int tid = threadIdx.x, lane = tid & 63, wid = tid >> 6;
  int wr = wid >> 1, wc = wid & 1;             // 4 x 2 waves of 64x64

  // XCD-affinity swizzle: XCD x = o&7 owns bm in [16x,16x+16) (one batch),
  // all 4 bhb panels -> each X panel fetched from HBM once per chip.
  int o = blockIdx.x;
  int x = o & 7, k = o >> 3;
  int bm = x * 16 + (k >> 2);                   // [0,128)
  int bhb = k & 3;                              // [0,4)

  f4v accz[4][4], acch[4][4];
#pragma unroll
  for (int i = 0; i < 4; i++)
#pragma unroll
    for (int j = 0; j < 4; j++) {
      accz[i][j] = (f4v){0.f, 0.f, 0.f, 0.f};
      acch[i][j] = (f4v){0.f, 0.f, 0.f, 0.f};
    }

  int r = tid >> 1, kh = tid & 1;               // staging role: row r, k32-half kh

  // issue X loads for step ks (32 fp32 = row r, k [ks*64+kh*32, +32))
  float4 xr[8];
  auto issueX = [&](int ks) {
    const float4* s = reinterpret_cast<const float4*>(
        X + (size_t)(bm * 256 + r) * Dn + ks * 64 + kh * 32);
#pragma unroll
    for (int j = 0; j < 8; j++) xr[j] = s[j];
  };
  // issue W DMA for step ks into buf
  auto issueW = [&](ushort_t* l, int ks) {
#pragma unroll
    for (int q = 0; q < 2; q++) {
      const ushort_t* sz = Wzb + ((size_t)bhb * 16 + 2 * ks + q) * 4096 + tid * 8;
      __builtin_amdgcn_global_load_lds((gv_t*)sz, (lv_t*)(l + 16384 + q * 4096 + tid * 8), 16, 0, 0);
      const ushort_t* sh = Whb + ((size_t)bhb * 16 + 2 * ks + q) * 4096 + tid * 8;
      __builtin_amdgcn_global_load_lds((gv_t*)sh, (lv_t*)(l + 24576 + q * 4096 + tid * 8), 16, 0, 0);
    }
  };
  // convert xr -> bf16, write 4 fragment chunks (2-way bank aliasing = free)
  auto cvtWrite = [&](ushort_t* l) {
    const float* f = reinterpret_cast<const float*>(xr);
    unsigned d[16];
#pragma unroll
    for (int n = 0; n < 16; n++) {
      unsigned dw;
      asm volatile("v_cvt_pk_bf16_f32 %0, %1, %2" : "=v"(dw) : "v"(f[2 * n]), "v"(f[2 * n + 1]));
      d[n] = dw;
    }
    int cb = (r >> 7) * 1024 + kh * 512 + ((r >> 4) & 7) * 64 + (r & 15);
#pragma unroll
    for (int q = 0; q < 4; q++) {
      uint4 w = {d[4 * q], d[4 * q + 1], d[4 * q + 2], d[4 * q + 3]};
      *reinterpret_cast<uint4*>(&l[(size_t)(cb + q * 16) * 8]) = w;
    }
  };

  // prologue: stage step 0 into buf 0
  issueX(0);
  issueW(lds, 0);
  asm volatile("s_waitcnt vmcnt(4)" ::: "memory");
  cvtWrite(lds);
  asm volatile("s_waitcnt vmcnt(0) lgkmcnt(0)" ::: "memory");
  __builtin_amdgcn_sched_barrier(0);
  __builtin_amdgcn_s_barrier();

  for (int ks = 0; ks < 8; ks++) {
    ushort_t* lc = lds + (ks & 1) * 32768;
    ushort_t* ln = lds + ((ks & 1) ^ 1) * 32768;
    if (ks < 7) {
      issueX(ks + 1);                            // 8 dwordx4 -> regs
      issueW(ln, ks + 1);                        // 4 DMA -> next buf
    }
    __builtin_amdgcn_sched_barrier(0);

#pragma unroll
    for (int kk = 0; kk < 2; kk++) {
      s8v af[4], bzf[4], bhf[4];
#pragma unroll
      for (int i = 0; i < 4; i++) {
        int g = wr * 4 + i;
        af[i] = *reinterpret_cast<const s8v*>(&lc[(g >> 3) * 8192 + kk * 4096 + (g & 7) * 512 + lane * 8]);
      }
#pragma unroll
      for (int j = 0; j < 4; j++) {
        int gj = wc * 4 + j;
        bzf[j] = *reinterpret_cast<const s8v*>(&lc[16384 + kk * 4096 + gj * 512 + lane * 8]);
        bhf[j] = *reinterpret_cast<const s8v*>(&lc[24576 + kk * 4096 + gj * 512 + lane * 8]);
      }
      __builtin_amdgcn_s_setprio(1);
#pragma unroll
      for (int i = 0; i < 4; i++)
#pragma unroll
        for (int j = 0; j < 4; j++) {
          accz[i][j] = __builtin_amdgcn_mfma_f32_16x16x32_bf16(af[i], bzf[j], accz[i][j], 0, 0, 0);
          acch[i][j] = __builtin_amdgcn_mfma_f32_16x16x32_bf16(af[i], bhf[j], acch[i][j], 0, 0, 0);
        }
      __builtin_amdgcn_s_setprio(0);
    }

    if (ks < 7) {
      asm volatile("s_waitcnt vmcnt(4)" ::: "memory");   // X regs landed (W DMA may remain)
      cvtWrite(ln);
      asm volatile("s_waitcnt vmcnt(0)" ::: "memory");   // W DMA landed
    }
    asm volatile("s_waitcnt lgkmcnt(0)" ::: "memory");   // ds_writes visible
    __builtin_amdgcn_sched_barrier(0);
    __builtin_amdgcn_s_barrier();                        // next buf ready; cur free
  }

  // ---- epilogue: C/D layout col=lane&15, row=(lane>>4)*4+q  [m89/m91] ----
  int R = bm * 4 + wr, Cc = bhb * 2 + wc;
  size_t base = (size_t)(R * 8 + Cc) * 1024;
  float bzv[4], bhv[4];
#pragma unroll
  for (int j = 0; j < 4; j++) {
    int h = bhb * 128 + wc * 64 + j * 16 + (lane & 15);
    bzv[j] = bzp[h];
    bhv[j] = bhp[h];
  }
  float QA[4][4], QB[4][4];   // per-(i,j) 4-t composites from ROUNDED fp16 a,b
#pragma unroll
  for (int i = 0; i < 4; i++)
#pragma unroll
    for (int j = 0; j < 4; j++) {
      h8v g;
      float Pa = 1.f, Pb = 0.f;
#pragma unroll
      for (int q = 0; q < 4; q++) {
        float z = 1.f / (1.f + __expf(-(accz[i][j][q] + bzv[j])));
        float e = __expf(2.f * (acch[i][j][q] + bhv[j]));
        float th = 1.f - 2.f / (e + 1.f);
        g[q] = (_Float16)(1.f - z);        // a_t
        g[4 + q] = (_Float16)(z * th);     // b_t
        float a = (float)g[q], b = (float)g[4 + q];
        Pa = a * Pa;                        // t ascending within lane (q)
        Pb = a * Pb + b;
      }
      cab[base + (size_t)((i * 4 + j) * 64 + lane)] = g;
      QA[i][j] = Pa;
      QB[i][j] = Pb;
    }

  // fused chunk summary: compose over lane-groups g=(lane>>4) then i, per j.
#pragma unroll
  for (int j = 0; j < 4; j++) {
    float A = 1.f, Bv = 0.f;
#pragma unroll
    for (int i = 0; i < 4; i++) {
      float a = QA[i][j], b = QB[i][j];
      float ap = __shfl_xor(a, 16), bp = __shfl_xor(b, 16);
      bool hi = (lane & 16) != 0;
      float af_ = hi ? ap : a, bf_ = hi ? bp : b;   // earlier segment
      float as_ = hi ? a : ap, bs_ = hi ? b : bp;   // later segment
      a = as_ * af_; b = as_ * bf_ + bs_;
      ap = __shfl_xor(a, 32); bp = __shfl_xor(b, 32);
      bool hi2 = (lane & 32) != 0;
      af_ = hi2 ? ap : a; bf_ = hi2 ? bp : b;
      as_ = hi2 ? a : ap; bs_ = hi2 ? b : bp;
      a = as_ * af_; b = as_ * bf_ + bs_;
      Bv = a * Bv + b;
      A = a * A;
    }
    if (lane < 16) {
      int h = bhb * 128 + wc * 64 + j * 16 + lane;
      cA[(size_t)R * Hn + h] = A;
      cB[(size_t)R * Hn + h] = Bv;
    }
  }
}

// S2: serial scan over 64 chunk summaries per (b,h) -> h_start per chunk
__global__ __launch_bounds__(256) void scan_heads(
    const float* __restrict__ cA, const float* __restrict__ cB,
    const float* __restrict__ h0p, float* __restrict__ hst) {
  int gid = blockIdx.x * 256 + threadIdx.x;   // 4096 = B*H
  int b = gid >> 9, h = gid & 511;
  float hr = h0p[(size_t)b * Hn + h];
#pragma unroll 8
  for (int c = 0; c < NC; c++) {
    size_t o = (size_t)(b * NC + c) * Hn + h;
    hst[o] = hr;
    hr = fmaf(cA[o], hr, cB[o]);
  }
}

// S3: replay each chunk from its h_start, write fp32 outputs (B,T,H)
__global__ __launch_bounds__(256) void scan_apply(
    const h8v* __restrict__ cab, const float* __restrict__ hst,
    float* __restrict__ out) {
  int h = blockIdx.y * 256 + threadIdx.x;
  int R = blockIdx.x;
  int hl = h & 63, Cc = h >> 6;
  size_t base = (size_t)(R * 8 + Cc) * 1024 + (size_t)(hl >> 4) * 64 + (hl & 15);
  float hr = hst[(size_t)R * Hn + h];
  size_t ob = (size_t)R * 64 * Hn + h;
#pragma unroll
  for (int i = 0; i < 4; i++)
#pragma unroll
    for (int p = 0; p < 4; p++) {
      h8v g = cab[base + i * 256 + p * 16];
#pragma unroll
      for (int q = 0; q < 4; q++) {
        hr = fmaf((float)g[q], hr, (float)g[4 + q]);
        out[ob + (size_t)(i * 16 + p * 4 + q) * Hn] = hr;
      }
    }
}

extern "C" void kernel_launch(void* const* d_in, const int* in_sizes, int n_in,
                              void* d_out, int out_size, void* d_ws, size_t ws_size,
                              hipStream_t stream) {
  const float* X   = (const float*)d_in[0];
  const float* h0p = (const float*)d_in[1];
  const float* Wz  = (const float*)d_in[2];
  const float* bz  = (const float*)d_in[3];
  const float* Wh  = (const float*)d_in[4];
  const float* bh  = (const float*)d_in[5];
  float* out = (float*)d_out;

  char* ws = (char*)d_ws;
  ushort_t* Wzb = (ushort_t*)ws;                                  // 0.5 MB
  ushort_t* Whb = Wzb + (size_t)Hn * Dn;                          // 0.5 MB
  h8v* cab      = (h8v*)(Whb + (size_t)Hn * Dn);                  // 67.1 MB
  // cab = 2*Mn*Hn halves = Mn*Hn/4 granules of 16B
  float* cA     = (float*)(cab + (size_t)Mn * Hn / 4);            // 1 MB
  float* cB     = cA + (size_t)Bn * NC * Hn;                      // 1 MB
  float* hst    = cB + (size_t)Bn * NC * Hn;                      // 1 MB

  convert_w<<<dim3(128), 256, 0, stream>>>(Wz, Wh, Wzb, Whb);

  gemm_act<<<dim3(512), 512, 0, stream>>>(X, Wzb, Whb, bz, bh, cab, cA, cB);

  scan_heads<<<dim3(Bn * Hn / 256), 256, 0, stream>>>(cA, cB, h0p, hst);
  scan_apply<<<dim3(Mn / 64, Hn / 256), 256, 0, stream>>>(cab, hst, out);
}

// Round 9
// 95.661 us; speedup vs baseline: 1.1291x; 1.1291x over previous
//
#include <hip/hip_runtime.h>

constexpr int Bn = 8, Tn = 4096, Dn = 512, Hn = 512;
constexpr int Mn = Bn * Tn;            // 32768 rows
constexpr int CH = 64, NC = Tn / CH;   // 64 chunks of 64 steps

typedef __attribute__((ext_vector_type(8))) short s8v;       // 8 bf16
typedef __attribute__((ext_vector_type(4))) float f4v;       // MFMA acc
typedef __attribute__((ext_vector_type(8))) _Float16 h8v;    // 16B granule: a[0..3], b[0..3]
typedef unsigned short ushort_t;

typedef __attribute__((address_space(1))) const void gv_t;   // global src for load_lds
typedef __attribute__((address_space(3))) void lv_t;         // LDS dst for load_lds

__device__ __forceinline__ short f2bf(float f) {
  unsigned u = __float_as_uint(f);
  u = (u + 0x7fffu + ((u >> 16) & 1u)) >> 16;   // RNE
  return (short)u;
}

// fp32 [rows][512] -> bf16 tiles of 128 rows x 32 k in MFMA-fragment order.
// Tile lb = rt*16 + kt; chunk c = (r>>4)*64 + k8*16 + (r&15), 16B each.
__global__ __launch_bounds__(256) void convert_x(
    const float* __restrict__ X, ushort_t* __restrict__ Xb) {
  int lb = blockIdx.x, tid = threadIdx.x;
  const float* tsrc = X + ((size_t)(lb >> 4) * 128) * Dn + (lb & 15) * 32;
#pragma unroll
  for (int p = 0; p < 2; p++) {
    int idx = tid + p * 256;
    int r = idx >> 2, k8 = idx & 3;
    const float4* sv = reinterpret_cast<const float4*>(tsrc + (size_t)r * Dn + k8 * 8);
    float4 f0 = sv[0], f1 = sv[1];
    s8v v;
    v[0] = f2bf(f0.x); v[1] = f2bf(f0.y); v[2] = f2bf(f0.z); v[3] = f2bf(f0.w);
    v[4] = f2bf(f1.x); v[5] = f2bf(f1.y); v[6] = f2bf(f1.z); v[7] = f2bf(f1.w);
    int c = (r >> 4) * 64 + k8 * 16 + (r & 15);
    *reinterpret_cast<s8v*>(&Xb[((size_t)lb * 512 + c) * 8]) = v;
  }
}

// Same for W. Blocks [0,64) = Wz, [64,128) = Wh.
__global__ __launch_bounds__(256) void convert_w(
    const float* __restrict__ Wz, const float* __restrict__ Wh,
    ushort_t* __restrict__ Wzb, ushort_t* __restrict__ Whb) {
  int bx = blockIdx.x, tid = threadIdx.x;
  const float* src;
  ushort_t* dst;
  int lb;
  if (bx < 64) { src = Wz; dst = Wzb; lb = bx; }
  else         { src = Wh; dst = Whb; lb = bx - 64; }
  const float* tsrc = src + ((size_t)(lb >> 4) * 128) * Dn + (lb & 15) * 32;
#pragma unroll
  for (int p = 0; p < 2; p++) {
    int idx = tid + p * 256;
    int r = idx >> 2, k8 = idx & 3;
    const float4* sv = reinterpret_cast<const float4*>(tsrc + (size_t)r * Dn + k8 * 8);
    float4 f0 = sv[0], f1 = sv[1];
    s8v v;
    v[0] = f2bf(f0.x); v[1] = f2bf(f0.y); v[2] = f2bf(f0.z); v[3] = f2bf(f0.w);
    v[4] = f2bf(f1.x); v[5] = f2bf(f1.y); v[6] = f2bf(f1.z); v[7] = f2bf(f1.w);
    int c = (r >> 4) * 64 + k8 * 16 + (r & 15);
    *reinterpret_cast<s8v*>(&dst[((size_t)lb * 512 + c) * 8]) = v;
  }
}

// W-stationary barrier-free dual GEMM + activations + chunk summaries.
// Block = (mt, p): 512 M-rows x 64 H-cols. Stages panel p's FULL W_z,W_h
// (K=512) into 128KB LDS once (1 barrier total), then K-loop with no
// barriers: W via broadcast ds_read, X reg-direct from pre-swizzled Xb
// (2-deep manual prefetch). 8 waves; wave = 64 rows (one chunk) x 64 cols.
__global__ __launch_bounds__(512, 2) void gemm_act(
    const ushort_t* __restrict__ Xb, const ushort_t* __restrict__ Wzb,
    const ushort_t* __restrict__ Whb,
    const float* __restrict__ bzp, const float* __restrict__ bhp,
    h8v* __restrict__ cab, float* __restrict__ cA, float* __restrict__ cB) {
  __shared__ __align__(16) ushort_t lds[32 * 2048];   // 32 regions x 4KB = 128KB

  int tid = threadIdx.x, lane = tid & 63, wid = tid >> 6;

  // XCD-affinity: XCD x owns mt in [8x, 8x+8); 8 panels of one mt adjacent.
  int o = blockIdx.x;
  int loc = o >> 3;
  int mt = (o & 7) * 8 + (loc >> 3);            // [0,64)  M-tile of 512 rows
  int p = loc & 7;                              // [0,8)   64-col H-panel

  // ---- stage W panel: region r = m*16+kt (m: 0=Wz,1=Wh), 4KB each ----
#pragma unroll
  for (int q = 0; q < 16; q++) {
    int r = q * 2 + (wid >> 2);                 // wave-uniform region id
    int kt = r & 15;
    const ushort_t* wsrc = (r >= 16 ? Whb : Wzb);
    const ushort_t* s = wsrc + ((size_t)((p >> 1) * 16 + kt)) * 4096 + (p & 1) * 2048 + (tid & 255) * 8;
    __builtin_amdgcn_global_load_lds((gv_t*)s, (lv_t*)(lds + r * 2048 + (tid & 255) * 8), 16, 0, 0);
  }

  f4v accz[4][4], acch[4][4];
#pragma unroll
  for (int i = 0; i < 4; i++)
#pragma unroll
    for (int j = 0; j < 4; j++) {
      accz[i][j] = (f4v){0.f, 0.f, 0.f, 0.f};
      acch[i][j] = (f4v){0.f, 0.f, 0.f, 0.f};
    }

  int rw = mt * 8 + wid;                        // global chunk id R [0,512)
  int rt = rw >> 1, half = rw & 1;              // Xb 128-row tile, half select
  const ushort_t* xb = Xb + (size_t)rt * 16 * 4096;

  __syncthreads();                              // W resident; read-only hereafter

  auto ldW = [&](int kt, s8v* bzf, s8v* bhf) {
#pragma unroll
    for (int j = 0; j < 4; j++) {
      bzf[j] = *reinterpret_cast<const s8v*>(lds + (size_t)kt * 2048 + (j * 64 + lane) * 8);
      bhf[j] = *reinterpret_cast<const s8v*>(lds + (size_t)(16 + kt) * 2048 + (j * 64 + lane) * 8);
    }
  };
  auto mfmaStep = [&](s8v* af, s8v* bzf, s8v* bhf) {
    __builtin_amdgcn_s_setprio(1);
#pragma unroll
    for (int i = 0; i < 4; i++)
#pragma unroll
      for (int j = 0; j < 4; j++) {
        accz[i][j] = __builtin_amdgcn_mfma_f32_16x16x32_bf16(af[i], bzf[j], accz[i][j], 0, 0, 0);
        acch[i][j] = __builtin_amdgcn_mfma_f32_16x16x32_bf16(af[i], bhf[j], acch[i][j], 0, 0, 0);
      }
    __builtin_amdgcn_s_setprio(0);
  };

  s8v afA[4], afB[4];
#pragma unroll
  for (int i = 0; i < 4; i++)
    afA[i] = *reinterpret_cast<const s8v*>(xb + ((half * 4 + i) * 64 + lane) * 8);

#pragma unroll
  for (int kp = 0; kp < 8; kp++) {
    int k0 = 2 * kp;
#pragma unroll
    for (int i = 0; i < 4; i++)
      afB[i] = *reinterpret_cast<const s8v*>(xb + (size_t)(k0 + 1) * 4096 + ((half * 4 + i) * 64 + lane) * 8);
    s8v bz0[4], bh0[4];
    ldW(k0, bz0, bh0);
    mfmaStep(afA, bz0, bh0);
    if (k0 + 2 < 16) {
#pragma unroll
      for (int i = 0; i < 4; i++)
        afA[i] = *reinterpret_cast<const s8v*>(xb + (size_t)(k0 + 2) * 4096 + ((half * 4 + i) * 64 + lane) * 8);
    }
    s8v bz1[4], bh1[4];
    ldW(k0 + 1, bz1, bh1);
    mfmaStep(afB, bz1, bh1);
  }

  // ---- epilogue: C/D layout col=lane&15, row=(lane>>4)*4+q  [m89/m91] ----
  int R = rw, Cc = p;
  size_t base = (size_t)(R * 8 + Cc) * 1024;
  float bzv[4], bhv[4];
#pragma unroll
  for (int j = 0; j < 4; j++) {
    int h = p * 64 + j * 16 + (lane & 15);
    bzv[j] = bzp[h];
    bhv[j] = bhp[h];
  }
  float QA[4][4], QB[4][4];   // per-(i,j) 4-t composites from ROUNDED fp16 a,b
#pragma unroll
  for (int i = 0; i < 4; i++)
#pragma unroll
    for (int j = 0; j < 4; j++) {
      h8v g;
      float Pa = 1.f, Pb = 0.f;
#pragma unroll
      for (int q = 0; q < 4; q++) {
        float z = 1.f / (1.f + __expf(-(accz[i][j][q] + bzv[j])));
        float e = __expf(2.f * (acch[i][j][q] + bhv[j]));
        float th = 1.f - 2.f / (e + 1.f);
        g[q] = (_Float16)(1.f - z);        // a_t
        g[4 + q] = (_Float16)(z * th);     // b_t
        float a = (float)g[q], b = (float)g[4 + q];
        Pa = a * Pa;                        // t ascending within lane (q)
        Pb = a * Pb + b;
      }
      cab[base + (size_t)((i * 4 + j) * 64 + lane)] = g;
      QA[i][j] = Pa;
      QB[i][j] = Pb;
    }

  // fused chunk summary: compose over lane-groups g=(lane>>4) then i, per j.
#pragma unroll
  for (int j = 0; j < 4; j++) {
    float A = 1.f, Bv = 0.f;
#pragma unroll
    for (int i = 0; i < 4; i++) {
      float a = QA[i][j], b = QB[i][j];
      float ap = __shfl_xor(a, 16), bp = __shfl_xor(b, 16);
      bool hi = (lane & 16) != 0;
      float af_ = hi ? ap : a, bf_ = hi ? bp : b;   // earlier segment
      float as_ = hi ? a : ap, bs_ = hi ? b : bp;   // later segment
      a = as_ * af_; b = as_ * bf_ + bs_;
      ap = __shfl_xor(a, 32); bp = __shfl_xor(b, 32);
      bool hi2 = (lane & 32) != 0;
      af_ = hi2 ? ap : a; bf_ = hi2 ? bp : b;
      as_ = hi2 ? a : ap; bs_ = hi2 ? b : bp;
      a = as_ * af_; b = as_ * bf_ + bs_;
      Bv = a * Bv + b;
      A = a * A;
    }
    if (lane < 16) {
      int h = p * 64 + j * 16 + lane;
      cA[(size_t)R * Hn + h] = A;
      cB[(size_t)R * Hn + h] = Bv;
    }
  }
}

// S2: serial scan over 64 chunk summaries per (b,h) -> h_start per chunk
__global__ __launch_bounds__(256) void scan_heads(
    const float* __restrict__ cA, const float* __restrict__ cB,
    const float* __restrict__ h0p, float* __restrict__ hst) {
  int gid = blockIdx.x * 256 + threadIdx.x;   // 4096 = B*H
  int b = gid >> 9, h = gid & 511;
  float hr = h0p[(size_t)b * Hn + h];
#pragma unroll 8
  for (int c = 0; c < NC; c++) {
    size_t o = (size_t)(b * NC + c) * Hn + h;
    hst[o] = hr;
    hr = fmaf(cA[o], hr, cB[o]);
  }
}

// S3: replay each chunk from its h_start, write fp32 outputs (B,T,H)
__global__ __launch_bounds__(256) void scan_apply(
    const h8v* __restrict__ cab, const float* __restrict__ hst,
    float* __restrict__ out) {
  int h = blockIdx.y * 256 + threadIdx.x;
  int R = blockIdx.x;
  int hl = h & 63, Cc = h >> 6;
  size_t base = (size_t)(R * 8 + Cc) * 1024 + (size_t)(hl >> 4) * 64 + (hl & 15);
  float hr = hst[(size_t)R * Hn + h];
  size_t ob = (size_t)R * 64 * Hn + h;
#pragma unroll
  for (int i = 0; i < 4; i++)
#pragma unroll
    for (int p = 0; p < 4; p++) {
      h8v g = cab[base + i * 256 + p * 16];
#pragma unroll
      for (int q = 0; q < 4; q++) {
        hr = fmaf((float)g[q], hr, (float)g[4 + q]);
        out[ob + (size_t)(i * 16 + p * 4 + q) * Hn] = hr;
      }
    }
}

extern "C" void kernel_launch(void* const* d_in, const int* in_sizes, int n_in,
                              void* d_out, int out_size, void* d_ws, size_t ws_size,
                              hipStream_t stream) {
  const float* X   = (const float*)d_in[0];
  const float* h0p = (const float*)d_in[1];
  const float* Wz  = (const float*)d_in[2];
  const float* bz  = (const float*)d_in[3];
  const float* Wh  = (const float*)d_in[4];
  const float* bh  = (const float*)d_in[5];
  float* out = (float*)d_out;

  char* ws = (char*)d_ws;
  ushort_t* Xb  = (ushort_t*)ws;                                  // 33.6 MB
  ushort_t* Wzb = Xb + (size_t)Mn * Dn;                           // 0.5 MB
  ushort_t* Whb = Wzb + (size_t)Hn * Dn;                          // 0.5 MB
  h8v* cab      = (h8v*)(Whb + (size_t)Hn * Dn);                  // 67.1 MB
  // cab = 2*Mn*Hn halves = Mn*Hn/4 granules of 16B
  float* cA     = (float*)(cab + (size_t)Mn * Hn / 4);            // 1 MB
  float* cB     = cA + (size_t)Bn * NC * Hn;                      // 1 MB
  float* hst    = cB + (size_t)Bn * NC * Hn;                      // 1 MB

  convert_x<<<dim3(4096), 256, 0, stream>>>(X, Xb);
  convert_w<<<dim3(128), 256, 0, stream>>>(Wz, Wh, Wzb, Whb);

  gemm_act<<<dim3(512), 512, 0, stream>>>(Xb, Wzb, Whb, bz, bh, cab, cA, cB);

  scan_heads<<<dim3(Bn * Hn / 256), 256, 0, stream>>>(cA, cB, h0p, hst);
  scan_apply<<<dim3(Mn / 64, Hn / 256), 256, 0, stream>>>(cab, hst, out);
}